// Round 10
// baseline (827.022 us; speedup 1.0000x reference)
//
#include <hip/hip_runtime.h>
#include <hip/hip_cooperative_groups.h>
#include <math.h>

namespace cg = cooperative_groups;

#define NN 50000
#define NE 800000
#define IN_CH 64
#define HEADS 8
#define OC 16
#define HID 128
#define NG 500
#define SCAN_B ((NN + 255) / 256)   // 196
#define CSR_G 1024                   // cooperative grid (<= co-residency cap)
#define LXP 68    // LDS X pitch (floats)
#define LWP 132   // LDS W pitch (floats)

__device__ __forceinline__ float leaky(float x) { return x > 0.f ? x : 0.2f * x; }

// round-to-nearest-even f32 -> bf16 (as ushort in low bits)
__device__ __forceinline__ unsigned bf16rn(float f) {
    unsigned u = __float_as_uint(f);
    return (u + 0x7fffu + ((u >> 16) & 1u)) >> 16;
}

// Sum across the 8-lane head group using DPP (VALU pipe, no LDS).
__device__ __forceinline__ float dpp8_sum(float x) {
    int t;
    t = __builtin_amdgcn_update_dpp(0, __float_as_int(x), 0xB1, 0xF, 0xF, true);  // quad_perm [1,0,3,2]
    x += __int_as_float(t);
    t = __builtin_amdgcn_update_dpp(0, __float_as_int(x), 0x4E, 0xF, 0xF, true);  // quad_perm [2,3,0,1]
    x += __int_as_float(t);
    t = __builtin_amdgcn_update_dpp(0, __float_as_int(x), 0x141, 0xF, 0xF, true); // row_half_mirror
    x += __int_as_float(t);
    return x;
}

// ---------------- Tiled GEMM: xlh(bf16) = x@Wl+bl; xr,xres fp32 -------------
__global__ __launch_bounds__(256) void k_gemm(
    const float* __restrict__ x,
    const float* __restrict__ Wl, const float* __restrict__ bl,
    const float* __restrict__ Wr, const float* __restrict__ br,
    const float* __restrict__ Wres,
    unsigned short* __restrict__ xlh, float* __restrict__ xr,
    float* __restrict__ xres)
{
    __shared__ float sX[64 * LXP];   // [node][k]
    __shared__ float sW[64 * LWP];   // [k][col]
    const int tid = threadIdx.x;
    const int n0 = blockIdx.x * 64;

    {
        const int r = tid >> 4;              // 0..15
        const int k4 = (tid & 15) * 4;
#pragma unroll
        for (int i = 0; i < 4; ++i) {
            const int node = n0 + i * 16 + r;
            float4 v = make_float4(0.f, 0.f, 0.f, 0.f);
            if (node < NN) v = *(const float4*)(x + (size_t)node * IN_CH + k4);
            *(float4*)(sX + (i * 16 + r) * LXP + k4) = v;
        }
    }

    const int tx = tid & 15;                 // col group: cols tx*8..+7
    const int ty = tid >> 4;                 // node group: nodes ty*4..+3
    const int c0 = tx * 8;

    for (int mtx = 0; mtx < 3; ++mtx) {
        const float* __restrict__ W = (mtx == 0) ? Wl : (mtx == 1) ? Wr : Wres;

        __syncthreads();
#pragma unroll
        for (int i = 0; i < 8; ++i) {
            const int idx = i * 256 + tid;   // float4 index in [64][32]
            const int k = idx >> 5;
            const int c4 = (idx & 31) * 4;
            const float4 v = *(const float4*)(W + k * HID + c4);
            *(float4*)(sW + k * LWP + c4) = v;
        }
        __syncthreads();

        float acc[4][8];
#pragma unroll
        for (int n = 0; n < 4; ++n)
#pragma unroll
            for (int c = 0; c < 8; ++c) acc[n][c] = 0.f;

        for (int k = 0; k < 64; k += 4) {
            float a[4][4];
#pragma unroll
            for (int n = 0; n < 4; ++n) {
                const float4 t = *(const float4*)(sX + (ty * 4 + n) * LXP + k);
                a[n][0] = t.x; a[n][1] = t.y; a[n][2] = t.z; a[n][3] = t.w;
            }
#pragma unroll
            for (int kk = 0; kk < 4; ++kk) {
                const float4 p0 = *(const float4*)(sW + (k + kk) * LWP + c0);
                const float4 p1 = *(const float4*)(sW + (k + kk) * LWP + c0 + 4);
                const float bv[8] = {p0.x, p0.y, p0.z, p0.w, p1.x, p1.y, p1.z, p1.w};
#pragma unroll
                for (int n = 0; n < 4; ++n) {
                    const float av = a[n][kk];
#pragma unroll
                    for (int c = 0; c < 8; ++c) acc[n][c] += av * bv[c];
                }
            }
        }

        if (mtx == 0) {
            float bias8[8];
#pragma unroll
            for (int c = 0; c < 8; ++c) bias8[c] = bl[c0 + c];
#pragma unroll
            for (int n = 0; n < 4; ++n) {
                const int node = n0 + ty * 4 + n;
                if (node < NN) {
                    uint4 pk;
                    unsigned* pp = &pk.x;
#pragma unroll
                    for (int c = 0; c < 4; ++c) {
                        const unsigned lo = bf16rn(acc[n][2 * c] + bias8[2 * c]);
                        const unsigned hi = bf16rn(acc[n][2 * c + 1] + bias8[2 * c + 1]);
                        pp[c] = lo | (hi << 16);
                    }
                    *(uint4*)(xlh + (size_t)node * HID + c0) = pk;
                }
            }
        } else {
            float* __restrict__ outp = (mtx == 1) ? xr : xres;
            float bias8[8];
#pragma unroll
            for (int c = 0; c < 8; ++c) bias8[c] = (mtx == 1) ? br[c0 + c] : 0.f;
#pragma unroll
            for (int n = 0; n < 4; ++n) {
                const int node = n0 + ty * 4 + n;
                if (node < NN) {
                    float4 o0, o1;
                    o0.x = acc[n][0] + bias8[0]; o0.y = acc[n][1] + bias8[1];
                    o0.z = acc[n][2] + bias8[2]; o0.w = acc[n][3] + bias8[3];
                    o1.x = acc[n][4] + bias8[4]; o1.y = acc[n][5] + bias8[5];
                    o1.z = acc[n][6] + bias8[6]; o1.w = acc[n][7] + bias8[7];
                    *(float4*)(outp + (size_t)node * HID + c0) = o0;
                    *(float4*)(outp + (size_t)node * HID + c0 + 4) = o1;
                }
            }
        }
    }
}

__device__ __forceinline__ int block_scan_excl(int v, int tid, int* ws)
{
    const int lane = tid & 63, w = tid >> 6;
    int incl = v;
#pragma unroll
    for (int d = 1; d < 64; d <<= 1) {
        int t = __shfl_up(incl, d, 64);
        if (lane >= d) incl += t;
    }
    if (lane == 63) ws[w] = incl;
    __syncthreads();
    int off = 0;
    for (int j = 0; j < w; ++j) off += ws[j];
    return off + incl - v;
}

// ---------------- Fused CSR build (cooperative): zero+deg+scan+scatter ------
// R9 evidence: ~160 us unaccounted outside top-5 kernels = dispatch gaps +
// the 6-kernel CSR chain. One cooperative kernel with grid.sync() removes
// 5 launch boundaries.
__global__ __launch_bounds__(256) void k_csr(
    const int* __restrict__ ei, int* __restrict__ deg,
    int* __restrict__ bsum, int* __restrict__ boff,
    int* __restrict__ row_ptr, int* __restrict__ cursor,
    int* __restrict__ col_src)
{
    cg::grid_group grid = cg::this_grid();
    __shared__ int ws[4];
    const int tid = threadIdx.x;
    const int b = blockIdx.x;
    const int gt = b * 256 + tid;
    const int NT = CSR_G * 256;

    // phase 0: zero degrees
    for (int i = gt; i < NN; i += NT) deg[i] = 0;
    grid.sync();

    // phase 1: degree histogram
    for (int e = gt; e < NE; e += NT) {
        const int d = ei[NE + e];
        if ((unsigned)d < NN) atomicAdd(&deg[d], 1);
    }
    grid.sync();

    // phase 2a: per-block scan
    if (b < SCAN_B) {
        const int i = b * 256 + tid;
        const int v = (i < NN) ? deg[i] : 0;
        const int excl = block_scan_excl(v, tid, ws);
        if (tid == 255) bsum[b] = excl + v;
    }
    grid.sync();

    // phase 2b: scan of block sums (block 0)
    if (b == 0) {
        const int v = (tid < SCAN_B) ? bsum[tid] : 0;
        const int excl = block_scan_excl(v, tid, ws);
        if (tid < SCAN_B) boff[tid] = excl;
        if (tid == 0) row_ptr[NN] = NE;
    }
    grid.sync();

    // phase 2c: add block offsets, write row_ptr + cursor
    if (b < SCAN_B) {
        const int i = b * 256 + tid;
        const int v = (i < NN) ? deg[i] : 0;
        const int excl = block_scan_excl(v, tid, ws) + boff[b];
        if (i < NN) { row_ptr[i] = excl; cursor[i] = excl; }
    }
    grid.sync();

    // phase 3: scatter sources into CSR order
    for (int e = gt; e < NE; e += NT) {
        const int s = ei[e];
        const int d = ei[NE + e];
        if ((unsigned)d >= NN) continue;
        const int pos = atomicAdd(&cursor[d], 1);
        if ((unsigned)pos < NE) col_src[pos] = s;
    }
}

// ---- Fused attention: single-pass softmax-aggregate, bf16 gather payload ----
__global__ __launch_bounds__(256) void k_agg(
    const unsigned short* __restrict__ xlh, const float* __restrict__ xr,
    const float* __restrict__ xres,
    const int* __restrict__ row_ptr, const int* __restrict__ col_src,
    const float* __restrict__ att, const float* __restrict__ bias,
    float* __restrict__ hfeat)
{
    const int lane = threadIdx.x & 63;
    const int wid = __builtin_amdgcn_readfirstlane((blockIdx.x * blockDim.x + threadIdx.x) >> 6);
    const int nw = (gridDim.x * blockDim.x) >> 6;
    const int c0 = lane * 2;
    const int hh = lane >> 3;
    const int ci = (lane & 7) * 2;
    const float a0 = att[hh * OC + ci];
    const float a1 = att[hh * OC + ci + 1];
    const float b0 = bias[c0], b1 = bias[c0 + 1];

    for (int n = wid; n < NN; n += nw) {
        int beg = row_ptr[n], end = row_ptr[n + 1];      // uniform s_loads
        beg = max(beg, 0); end = min(end, NE); if (end < beg) end = beg;  // defensive
        const float2 xrn = *(const float2*)(xr + (size_t)n * HID + c0);
        const unsigned vvn = *((const unsigned*)(xlh + (size_t)n * HID) + lane);
        const float xlnx = __uint_as_float(vvn << 16);
        const float xlny = __uint_as_float(vvn & 0xffff0000u);
        const float qs = dpp8_sum(leaky(xlnx + xrn.x) * a0 + leaky(xlny + xrn.y) * a1);

        float den = __expf(qs);                 // self-loop term
        float acc0 = den * xlnx, acc1 = den * xlny;

        for (int base = beg; base < end; base += 64) {
            const int cnt = min(64, end - base);
            int sidx = 0;
            if (base + lane < end) sidx = col_src[base + lane];
            if ((unsigned)sidx >= NN) sidx = 0;          // bound all gathers
            for (int j = 0; j < cnt; j += 16) {
                int s[16]; unsigned vv[16];
#pragma unroll
                for (int u = 0; u < 16; ++u) s[u] = __builtin_amdgcn_readlane(sidx, j + u);
#pragma unroll
                for (int u = 0; u < 16; ++u)
                    vv[u] = *((const unsigned*)(xlh + (size_t)s[u] * HID) + lane);
#pragma unroll
                for (int u = 0; u < 16; ++u) {
                    const float vx = __uint_as_float(vv[u] << 16);
                    const float vy = __uint_as_float(vv[u] & 0xffff0000u);
                    const float q = dpp8_sum(leaky(vx + xrn.x) * a0 +
                                             leaky(vy + xrn.y) * a1);
                    if (j + u < cnt) {
                        const float w = __expf(q);
                        den += w;
                        acc0 += w * vx;
                        acc1 += w * vy;
                    }
                }
            }
        }

        const float2 xrs = *(const float2*)(xres + (size_t)n * HID + c0);
        const float inv = 1.f / den;
        float2 t;
        t.x = acc0 * inv + xrs.x + b0;
        t.y = acc1 * inv + xrs.y + b1;
        *(float2*)(hfeat + (size_t)n * HID + c0) = t;
    }
}

// ---- Fused tail: per-graph {Wlin+ELU pool} + MLP (replaces post/pool/mlp) --
// One block per graph (batch sorted). Each thread handles whole nodes:
// h = elu(hfeat_row @ Wlin + blin), accumulated; block-reduce; then the
// 16->16->32->5 MLP from LDS-staged weights.
__global__ __launch_bounds__(256) void k_tail(
    const float* __restrict__ hfeat, const int* __restrict__ batch,
    const float* __restrict__ Wlin, const float* __restrict__ blin,
    const float* __restrict__ W1, const float* __restrict__ b1,
    const float* __restrict__ W2, const float* __restrict__ b2,
    const float* __restrict__ W3, const float* __restrict__ b3,
    float* __restrict__ out)
{
    __shared__ float sWlin[HID * 16];
    __shared__ float sblin[16];
    __shared__ float sW1[256], sb1[16], sW2[512], sb2[32], sW3[160], sb3[5];
    __shared__ float red[256][16];
    __shared__ float sg[16], sv1[16], sv2[32];
    const int g = blockIdx.x;
    const int tid = threadIdx.x;

    for (int i = tid; i < HID * 16; i += 256) sWlin[i] = Wlin[i];
    if (tid < 16)  sblin[tid] = blin[tid];
    if (tid < 256) sW1[tid] = W1[tid];
    for (int i = tid; i < 512; i += 256) sW2[i] = W2[i];
    if (tid < 160) sW3[tid] = W3[tid];
    if (tid < 16)  sb1[tid] = b1[tid];
    if (tid < 32)  sb2[tid] = b2[tid];
    if (tid < 5)   sb3[tid] = b3[tid];
    __syncthreads();

    // node range of this graph
    int lo = 0, hi = NN;
    while (lo < hi) { int mid = (lo + hi) >> 1; if (batch[mid] < g) lo = mid + 1; else hi = mid; }
    int lo2 = lo, hi2 = NN;
    while (lo2 < hi2) { int mid = (lo2 + hi2) >> 1; if (batch[mid] < g + 1) lo2 = mid + 1; else hi2 = mid; }
    const int nbeg = lo, nend = lo2;

    float sum16[16];
#pragma unroll
    for (int j = 0; j < 16; ++j) sum16[j] = 0.f;

    for (int n = nbeg + tid; n < nend; n += 256) {
        float acc[16];
#pragma unroll
        for (int j = 0; j < 16; ++j) acc[j] = sblin[j];
        const float4* hrow = (const float4*)(hfeat + (size_t)n * HID);
#pragma unroll 8
        for (int kc = 0; kc < 32; ++kc) {
            const float4 v = hrow[kc];
#pragma unroll
            for (int j = 0; j < 16; ++j) {
                acc[j] += v.x * sWlin[(kc * 4 + 0) * 16 + j] + v.y * sWlin[(kc * 4 + 1) * 16 + j]
                        + v.z * sWlin[(kc * 4 + 2) * 16 + j] + v.w * sWlin[(kc * 4 + 3) * 16 + j];
            }
        }
#pragma unroll
        for (int j = 0; j < 16; ++j) {
            float o = acc[j];
            o = o > 0.f ? o : __expf(o) - 1.f;
            sum16[j] += o;
        }
    }

#pragma unroll
    for (int j = 0; j < 16; ++j) red[tid][j] = sum16[j];
    __syncthreads();
    for (int s = 128; s > 0; s >>= 1) {
        if (tid < s) {
#pragma unroll
            for (int j = 0; j < 16; ++j) red[tid][j] += red[tid + s][j];
        }
        __syncthreads();
    }

    if (tid < 16) sg[tid] = red[0][tid] / fmaxf((float)(nend - nbeg), 1.f);
    __syncthreads();
    if (tid < 16) {
        float s = sb1[tid];
#pragma unroll
        for (int c = 0; c < 16; ++c) s += sg[c] * sW1[c * 16 + tid];
        sv1[tid] = fmaxf(s, 0.f);
    }
    __syncthreads();
    if (tid < 32) {
        float s = sb2[tid];
#pragma unroll
        for (int c = 0; c < 16; ++c) s += sv1[c] * sW2[c * 32 + tid];
        sv2[tid] = fmaxf(s, 0.f);
    }
    __syncthreads();
    if (tid < 5) {
        float s = sb3[tid];
#pragma unroll
        for (int c = 0; c < 32; ++c) s += sv2[c] * sW3[c * 5 + tid];
        out[g * 5 + tid] = s;
    }
}

extern "C" void kernel_launch(void* const* d_in, const int* in_sizes, int n_in,
                              void* d_out, int out_size, void* d_ws, size_t ws_size,
                              hipStream_t stream)
{
    const float* x    = (const float*)d_in[0];
    const int*   ei   = (const int*)d_in[1];
    const int*   batch= (const int*)d_in[2];
    const float* Wl   = (const float*)d_in[3];
    const float* bl   = (const float*)d_in[4];
    const float* Wr   = (const float*)d_in[5];
    const float* br   = (const float*)d_in[6];
    const float* att  = (const float*)d_in[7];
    const float* Wres = (const float*)d_in[8];
    const float* bias = (const float*)d_in[9];
    const float* Wlin = (const float*)d_in[10];
    const float* blin = (const float*)d_in[11];
    const float* W1   = (const float*)d_in[12];
    const float* b1   = (const float*)d_in[13];
    const float* W2   = (const float*)d_in[14];
    const float* b2   = (const float*)d_in[15];
    const float* W3   = (const float*)d_in[16];
    const float* b3   = (const float*)d_in[17];
    float* out = (float*)d_out;

    uintptr_t p = (uintptr_t)d_ws;
    unsigned short* xlh = (unsigned short*)p; p += (size_t)NN * HID * 2;
    p = (p + 15) & ~(uintptr_t)15;
    float* xr     = (float*)p; p += (size_t)NN * HID * 4;
    float* xres   = (float*)p; p += (size_t)NN * HID * 4;
    float* hfeat  = (float*)p; p += (size_t)NN * HID * 4;
    int* deg      = (int*)p;   p += (size_t)NN * 4;
    int* row_ptr  = (int*)p;   p += (size_t)(NN + 1) * 4;
    int* cursor   = (int*)p;   p += (size_t)NN * 4;
    int* col_src  = (int*)p;   p += (size_t)NE * 4;
    int* bsum     = (int*)p;   p += (size_t)SCAN_B * 4;
    int* boff     = (int*)p;   p += (size_t)SCAN_B * 4;

    k_gemm<<<(NN + 63) / 64, 256, 0, stream>>>(x, Wl, bl, Wr, br, Wres, xlh, xr, xres);

    {
        void* args[] = { (void*)&ei, (void*)&deg, (void*)&bsum, (void*)&boff,
                         (void*)&row_ptr, (void*)&cursor, (void*)&col_src };
        hipLaunchCooperativeKernel((const void*)k_csr, dim3(CSR_G), dim3(256),
                                   args, 0, stream);
    }

    k_agg<<<2048, 256, 0, stream>>>(xlh, xr, xres, row_ptr, col_src, att, bias, hfeat);

    k_tail<<<NG, 256, 0, stream>>>(hfeat, batch, Wlin, blin,
                                   W1, b1, W2, b2, W3, b3, out);
}

// Round 11
// 319.821 us; speedup vs baseline: 2.5859x; 2.5859x over previous
//
#include <hip/hip_runtime.h>
#include <math.h>

#define NN 50000
#define NE 800000
#define IN_CH 64
#define HEADS 8
#define OC 16
#define HID 128
#define NG 500
#define SCAN_B ((NN + 255) / 256)   // 196
#define LXP 68    // LDS X pitch (floats)
#define LWP 132   // LDS W pitch (floats)

__device__ __forceinline__ float leaky(float x) { return x > 0.f ? x : 0.2f * x; }

// round-to-nearest-even f32 -> bf16 (as ushort in low bits)
__device__ __forceinline__ unsigned bf16rn(float f) {
    unsigned u = __float_as_uint(f);
    return (u + 0x7fffu + ((u >> 16) & 1u)) >> 16;
}

// Sum across the 8-lane head group using DPP (VALU pipe, no LDS).
__device__ __forceinline__ float dpp8_sum(float x) {
    int t;
    t = __builtin_amdgcn_update_dpp(0, __float_as_int(x), 0xB1, 0xF, 0xF, true);  // quad_perm [1,0,3,2]
    x += __int_as_float(t);
    t = __builtin_amdgcn_update_dpp(0, __float_as_int(x), 0x4E, 0xF, 0xF, true);  // quad_perm [2,3,0,1]
    x += __int_as_float(t);
    t = __builtin_amdgcn_update_dpp(0, __float_as_int(x), 0x141, 0xF, 0xF, true); // row_half_mirror
    x += __int_as_float(t);
    return x;
}

// ---------------- Tiled GEMM: xlh(bf16) = x@Wl+bl; xr,xres fp32 -------------
// Epilogue also zeroes deg[] (saves the k_zero launch; stream-ordered
// before k_deg). R10 lesson: grid.sync() costs ~85us/sync on 8 XCDs —
// NEVER fuse via cooperative launch here; separate kernels are cheaper.
__global__ __launch_bounds__(256) void k_gemm(
    const float* __restrict__ x,
    const float* __restrict__ Wl, const float* __restrict__ bl,
    const float* __restrict__ Wr, const float* __restrict__ br,
    const float* __restrict__ Wres,
    unsigned short* __restrict__ xlh, float* __restrict__ xr,
    float* __restrict__ xres, int* __restrict__ deg)
{
    __shared__ float sX[64 * LXP];   // [node][k]
    __shared__ float sW[64 * LWP];   // [k][col]
    const int tid = threadIdx.x;
    const int n0 = blockIdx.x * 64;

    // zero deg for the CSR build (blocks 0..195 cover [0,50176))
    {
        const int zi = blockIdx.x * 256 + tid;
        if (blockIdx.x < SCAN_B && zi < NN) deg[zi] = 0;
    }

    {
        const int r = tid >> 4;              // 0..15
        const int k4 = (tid & 15) * 4;
#pragma unroll
        for (int i = 0; i < 4; ++i) {
            const int node = n0 + i * 16 + r;
            float4 v = make_float4(0.f, 0.f, 0.f, 0.f);
            if (node < NN) v = *(const float4*)(x + (size_t)node * IN_CH + k4);
            *(float4*)(sX + (i * 16 + r) * LXP + k4) = v;
        }
    }

    const int tx = tid & 15;                 // col group: cols tx*8..+7
    const int ty = tid >> 4;                 // node group: nodes ty*4..+3
    const int c0 = tx * 8;

    for (int mtx = 0; mtx < 3; ++mtx) {
        const float* __restrict__ W = (mtx == 0) ? Wl : (mtx == 1) ? Wr : Wres;

        __syncthreads();
#pragma unroll
        for (int i = 0; i < 8; ++i) {
            const int idx = i * 256 + tid;   // float4 index in [64][32]
            const int k = idx >> 5;
            const int c4 = (idx & 31) * 4;
            const float4 v = *(const float4*)(W + k * HID + c4);
            *(float4*)(sW + k * LWP + c4) = v;
        }
        __syncthreads();

        float acc[4][8];
#pragma unroll
        for (int n = 0; n < 4; ++n)
#pragma unroll
            for (int c = 0; c < 8; ++c) acc[n][c] = 0.f;

        for (int k = 0; k < 64; k += 4) {
            float a[4][4];
#pragma unroll
            for (int n = 0; n < 4; ++n) {
                const float4 t = *(const float4*)(sX + (ty * 4 + n) * LXP + k);
                a[n][0] = t.x; a[n][1] = t.y; a[n][2] = t.z; a[n][3] = t.w;
            }
#pragma unroll
            for (int kk = 0; kk < 4; ++kk) {
                const float4 p0 = *(const float4*)(sW + (k + kk) * LWP + c0);
                const float4 p1 = *(const float4*)(sW + (k + kk) * LWP + c0 + 4);
                const float bv[8] = {p0.x, p0.y, p0.z, p0.w, p1.x, p1.y, p1.z, p1.w};
#pragma unroll
                for (int n = 0; n < 4; ++n) {
                    const float av = a[n][kk];
#pragma unroll
                    for (int c = 0; c < 8; ++c) acc[n][c] += av * bv[c];
                }
            }
        }

        if (mtx == 0) {
            float bias8[8];
#pragma unroll
            for (int c = 0; c < 8; ++c) bias8[c] = bl[c0 + c];
#pragma unroll
            for (int n = 0; n < 4; ++n) {
                const int node = n0 + ty * 4 + n;
                if (node < NN) {
                    uint4 pk;
                    unsigned* pp = &pk.x;
#pragma unroll
                    for (int c = 0; c < 4; ++c) {
                        const unsigned lo = bf16rn(acc[n][2 * c] + bias8[2 * c]);
                        const unsigned hi = bf16rn(acc[n][2 * c + 1] + bias8[2 * c + 1]);
                        pp[c] = lo | (hi << 16);
                    }
                    *(uint4*)(xlh + (size_t)node * HID + c0) = pk;
                }
            }
        } else {
            float* __restrict__ outp = (mtx == 1) ? xr : xres;
            float bias8[8];
#pragma unroll
            for (int c = 0; c < 8; ++c) bias8[c] = (mtx == 1) ? br[c0 + c] : 0.f;
#pragma unroll
            for (int n = 0; n < 4; ++n) {
                const int node = n0 + ty * 4 + n;
                if (node < NN) {
                    float4 o0, o1;
                    o0.x = acc[n][0] + bias8[0]; o0.y = acc[n][1] + bias8[1];
                    o0.z = acc[n][2] + bias8[2]; o0.w = acc[n][3] + bias8[3];
                    o1.x = acc[n][4] + bias8[4]; o1.y = acc[n][5] + bias8[5];
                    o1.z = acc[n][6] + bias8[6]; o1.w = acc[n][7] + bias8[7];
                    *(float4*)(outp + (size_t)node * HID + c0) = o0;
                    *(float4*)(outp + (size_t)node * HID + c0 + 4) = o1;
                }
            }
        }
    }
}

// ---------------- CSR build (real edges ONLY; self-loops handled in k_agg) --
__global__ __launch_bounds__(256) void k_deg(const int* __restrict__ ei, int* __restrict__ deg)
{
    int e = blockIdx.x * blockDim.x + threadIdx.x;
    if (e < NE) {
        int d = ei[NE + e];
        if ((unsigned)d < NN) atomicAdd(&deg[d], 1);
    }
}

__device__ __forceinline__ int block_scan_excl(int v, int tid, int* ws)
{
    const int lane = tid & 63, w = tid >> 6;
    int incl = v;
#pragma unroll
    for (int d = 1; d < 64; d <<= 1) {
        int t = __shfl_up(incl, d, 64);
        if (lane >= d) incl += t;
    }
    if (lane == 63) ws[w] = incl;
    __syncthreads();
    int off = 0;
    for (int j = 0; j < w; ++j) off += ws[j];
    return off + incl - v;
}

__global__ __launch_bounds__(256) void k_scan1(const int* __restrict__ deg, int* __restrict__ bsum)
{
    __shared__ int ws[4];
    const int tid = threadIdx.x;
    const int i = blockIdx.x * 256 + tid;
    const int v = (i < NN) ? deg[i] : 0;
    int excl = block_scan_excl(v, tid, ws);
    if (tid == 255) bsum[blockIdx.x] = excl + v;
}

__global__ __launch_bounds__(256) void k_scan2(int* __restrict__ bsum, int* __restrict__ boff,
                                               int* __restrict__ row_ptr)
{
    __shared__ int ws[4];
    const int tid = threadIdx.x;
    const int v = (tid < SCAN_B) ? bsum[tid] : 0;
    int excl = block_scan_excl(v, tid, ws);
    if (tid < SCAN_B) boff[tid] = excl;
    if (tid == 0) row_ptr[NN] = NE;
}

__global__ __launch_bounds__(256) void k_scan3(const int* __restrict__ deg,
                                               const int* __restrict__ boff,
                                               int* __restrict__ row_ptr,
                                               int* __restrict__ cursor)
{
    __shared__ int ws[4];
    const int tid = threadIdx.x;
    const int i = blockIdx.x * 256 + tid;
    const int v = (i < NN) ? deg[i] : 0;
    int excl = block_scan_excl(v, tid, ws) + boff[blockIdx.x];
    if (i < NN) { row_ptr[i] = excl; cursor[i] = excl; }
}

__global__ __launch_bounds__(256) void k_scatter(const int* __restrict__ ei,
                                                 int* __restrict__ cursor,
                                                 int* __restrict__ col_src)
{
    int e = blockIdx.x * blockDim.x + threadIdx.x;
    if (e >= NE) return;
    const int s = ei[e];
    const int d = ei[NE + e];
    if ((unsigned)d >= NN) return;                       // defensive
    int pos = atomicAdd(&cursor[d], 1);
    if ((unsigned)pos < NE) col_src[pos] = s;            // never corrupt ws
}

// ---- Fused attention: single-pass softmax-aggregate, bf16 gather payload ----
__global__ __launch_bounds__(256) void k_agg(
    const unsigned short* __restrict__ xlh, const float* __restrict__ xr,
    const float* __restrict__ xres,
    const int* __restrict__ row_ptr, const int* __restrict__ col_src,
    const float* __restrict__ att, const float* __restrict__ bias,
    float* __restrict__ hfeat)
{
    const int lane = threadIdx.x & 63;
    const int wid = __builtin_amdgcn_readfirstlane((blockIdx.x * blockDim.x + threadIdx.x) >> 6);
    const int nw = (gridDim.x * blockDim.x) >> 6;
    const int c0 = lane * 2;
    const int hh = lane >> 3;
    const int ci = (lane & 7) * 2;
    const float a0 = att[hh * OC + ci];
    const float a1 = att[hh * OC + ci + 1];
    const float b0 = bias[c0], b1 = bias[c0 + 1];

    for (int n = wid; n < NN; n += nw) {
        int beg = row_ptr[n], end = row_ptr[n + 1];      // uniform s_loads
        beg = max(beg, 0); end = min(end, NE); if (end < beg) end = beg;  // defensive
        const float2 xrn = *(const float2*)(xr + (size_t)n * HID + c0);
        const unsigned vvn = *((const unsigned*)(xlh + (size_t)n * HID) + lane);
        const float xlnx = __uint_as_float(vvn << 16);
        const float xlny = __uint_as_float(vvn & 0xffff0000u);
        const float qs = dpp8_sum(leaky(xlnx + xrn.x) * a0 + leaky(xlny + xrn.y) * a1);

        float den = __expf(qs);                 // self-loop term
        float acc0 = den * xlnx, acc1 = den * xlny;

        for (int base = beg; base < end; base += 64) {
            const int cnt = min(64, end - base);
            int sidx = 0;
            if (base + lane < end) sidx = col_src[base + lane];
            if ((unsigned)sidx >= NN) sidx = 0;          // bound all gathers
            for (int j = 0; j < cnt; j += 16) {
                int s[16]; unsigned vv[16];
#pragma unroll
                for (int u = 0; u < 16; ++u) s[u] = __builtin_amdgcn_readlane(sidx, j + u);
#pragma unroll
                for (int u = 0; u < 16; ++u)
                    vv[u] = *((const unsigned*)(xlh + (size_t)s[u] * HID) + lane);
#pragma unroll
                for (int u = 0; u < 16; ++u) {
                    const float vx = __uint_as_float(vv[u] << 16);
                    const float vy = __uint_as_float(vv[u] & 0xffff0000u);
                    const float q = dpp8_sum(leaky(vx + xrn.x) * a0 +
                                             leaky(vy + xrn.y) * a1);
                    if (j + u < cnt) {
                        const float w = __expf(q);
                        den += w;
                        acc0 += w * vx;
                        acc1 += w * vy;
                    }
                }
            }
        }

        const float2 xrs = *(const float2*)(xres + (size_t)n * HID + c0);
        const float inv = 1.f / den;
        float2 t;
        t.x = acc0 * inv + xrs.x + b0;
        t.y = acc1 * inv + xrs.y + b1;
        *(float2*)(hfeat + (size_t)n * HID + c0) = t;
    }
}

// ---- Fused tail: per-graph {Wlin+ELU pool} + MLP ---------------------------
// red padded to [256][17]: stride-16 layout aliased to 2 banks (32-way
// conflicts in the tree reduction) — R10 suspect for k_tail slowness.
__global__ __launch_bounds__(256) void k_tail(
    const float* __restrict__ hfeat, const int* __restrict__ batch,
    const float* __restrict__ Wlin, const float* __restrict__ blin,
    const float* __restrict__ W1, const float* __restrict__ b1,
    const float* __restrict__ W2, const float* __restrict__ b2,
    const float* __restrict__ W3, const float* __restrict__ b3,
    float* __restrict__ out)
{
    __shared__ float sWlin[HID * 16];
    __shared__ float sblin[16];
    __shared__ float sW1[256], sb1[16], sW2[512], sb2[32], sW3[160], sb3[5];
    __shared__ float red[256][17];
    __shared__ float sg[16], sv1[16], sv2[32];
    const int g = blockIdx.x;
    const int tid = threadIdx.x;

    for (int i = tid; i < HID * 16; i += 256) sWlin[i] = Wlin[i];
    if (tid < 16)  sblin[tid] = blin[tid];
    if (tid < 256) sW1[tid] = W1[tid];
    for (int i = tid; i < 512; i += 256) sW2[i] = W2[i];
    if (tid < 160) sW3[tid] = W3[tid];
    if (tid < 16)  sb1[tid] = b1[tid];
    if (tid < 32)  sb2[tid] = b2[tid];
    if (tid < 5)   sb3[tid] = b3[tid];
    __syncthreads();

    // node range of this graph (batch sorted)
    int lo = 0, hi = NN;
    while (lo < hi) { int mid = (lo + hi) >> 1; if (batch[mid] < g) lo = mid + 1; else hi = mid; }
    int lo2 = lo, hi2 = NN;
    while (lo2 < hi2) { int mid = (lo2 + hi2) >> 1; if (batch[mid] < g + 1) lo2 = mid + 1; else hi2 = mid; }
    const int nbeg = lo, nend = lo2;

    float sum16[16];
#pragma unroll
    for (int j = 0; j < 16; ++j) sum16[j] = 0.f;

    for (int n = nbeg + tid; n < nend; n += 256) {
        float acc[16];
#pragma unroll
        for (int j = 0; j < 16; ++j) acc[j] = sblin[j];
        const float4* hrow = (const float4*)(hfeat + (size_t)n * HID);
#pragma unroll 8
        for (int kc = 0; kc < 32; ++kc) {
            const float4 v = hrow[kc];
#pragma unroll
            for (int j = 0; j < 16; ++j) {
                acc[j] += v.x * sWlin[(kc * 4 + 0) * 16 + j] + v.y * sWlin[(kc * 4 + 1) * 16 + j]
                        + v.z * sWlin[(kc * 4 + 2) * 16 + j] + v.w * sWlin[(kc * 4 + 3) * 16 + j];
            }
        }
#pragma unroll
        for (int j = 0; j < 16; ++j) {
            float o = acc[j];
            o = o > 0.f ? o : __expf(o) - 1.f;
            sum16[j] += o;
        }
    }

#pragma unroll
    for (int j = 0; j < 16; ++j) red[tid][j] = sum16[j];
    __syncthreads();
    for (int s = 128; s > 0; s >>= 1) {
        if (tid < s) {
#pragma unroll
            for (int j = 0; j < 16; ++j) red[tid][j] += red[tid + s][j];
        }
        __syncthreads();
    }

    if (tid < 16) sg[tid] = red[0][tid] / fmaxf((float)(nend - nbeg), 1.f);
    __syncthreads();
    if (tid < 16) {
        float s = sb1[tid];
#pragma unroll
        for (int c = 0; c < 16; ++c) s += sg[c] * sW1[c * 16 + tid];
        sv1[tid] = fmaxf(s, 0.f);
    }
    __syncthreads();
    if (tid < 32) {
        float s = sb2[tid];
#pragma unroll
        for (int c = 0; c < 16; ++c) s += sv1[c] * sW2[c * 32 + tid];
        sv2[tid] = fmaxf(s, 0.f);
    }
    __syncthreads();
    if (tid < 5) {
        float s = sb3[tid];
#pragma unroll
        for (int c = 0; c < 32; ++c) s += sv2[c] * sW3[c * 5 + tid];
        out[g * 5 + tid] = s;
    }
}

extern "C" void kernel_launch(void* const* d_in, const int* in_sizes, int n_in,
                              void* d_out, int out_size, void* d_ws, size_t ws_size,
                              hipStream_t stream)
{
    const float* x    = (const float*)d_in[0];
    const int*   ei   = (const int*)d_in[1];
    const int*   batch= (const int*)d_in[2];
    const float* Wl   = (const float*)d_in[3];
    const float* bl   = (const float*)d_in[4];
    const float* Wr   = (const float*)d_in[5];
    const float* br   = (const float*)d_in[6];
    const float* att  = (const float*)d_in[7];
    const float* Wres = (const float*)d_in[8];
    const float* bias = (const float*)d_in[9];
    const float* Wlin = (const float*)d_in[10];
    const float* blin = (const float*)d_in[11];
    const float* W1   = (const float*)d_in[12];
    const float* b1   = (const float*)d_in[13];
    const float* W2   = (const float*)d_in[14];
    const float* b2   = (const float*)d_in[15];
    const float* W3   = (const float*)d_in[16];
    const float* b3   = (const float*)d_in[17];
    float* out = (float*)d_out;

    uintptr_t p = (uintptr_t)d_ws;
    unsigned short* xlh = (unsigned short*)p; p += (size_t)NN * HID * 2;
    p = (p + 15) & ~(uintptr_t)15;
    float* xr     = (float*)p; p += (size_t)NN * HID * 4;
    float* xres   = (float*)p; p += (size_t)NN * HID * 4;
    float* hfeat  = (float*)p; p += (size_t)NN * HID * 4;
    int* deg      = (int*)p;   p += (size_t)NN * 4;
    int* row_ptr  = (int*)p;   p += (size_t)(NN + 1) * 4;
    int* cursor   = (int*)p;   p += (size_t)NN * 4;
    int* col_src  = (int*)p;   p += (size_t)NE * 4;
    int* bsum     = (int*)p;   p += (size_t)SCAN_B * 4;
    int* boff     = (int*)p;   p += (size_t)SCAN_B * 4;

    k_gemm<<<(NN + 63) / 64, 256, 0, stream>>>(x, Wl, bl, Wr, br, Wres, xlh, xr, xres, deg);
    k_deg<<<(NE + 255) / 256, 256, 0, stream>>>(ei, deg);
    k_scan1<<<SCAN_B, 256, 0, stream>>>(deg, bsum);
    k_scan2<<<1, 256, 0, stream>>>(bsum, boff, row_ptr);
    k_scan3<<<SCAN_B, 256, 0, stream>>>(deg, boff, row_ptr, cursor);
    k_scatter<<<(NE + 255) / 256, 256, 0, stream>>>(ei, cursor, col_src);
    k_agg<<<2048, 256, 0, stream>>>(xlh, xr, xres, row_ptr, col_src, att, bias, hfeat);
    k_tail<<<NG, 256, 0, stream>>>(hfeat, batch, Wlin, blin,
                                   W1, b1, W2, b2, W3, b3, out);
}

// Round 12
// 304.999 us; speedup vs baseline: 2.7116x; 1.0486x over previous
//
#include <hip/hip_runtime.h>
#include <math.h>

#define NN 50000
#define NE 800000
#define IN_CH 64
#define HEADS 8
#define OC 16
#define HID 128
#define NG 500
#define SCAN_B ((NN + 255) / 256)   // 196
#define GEMM_B ((NN + 63) / 64)     // 782
#define EPB 1024                    // edges histogrammed per gemm block
#define LXP 68    // LDS X pitch (floats)
#define LWP 132   // LDS W pitch (floats)

__device__ __forceinline__ float leaky(float x) { return x > 0.f ? x : 0.2f * x; }

// round-to-nearest-even f32 -> bf16 (as ushort in low bits)
__device__ __forceinline__ unsigned bf16rn(float f) {
    unsigned u = __float_as_uint(f);
    return (u + 0x7fffu + ((u >> 16) & 1u)) >> 16;
}

// Sum across the 8-lane head group using DPP (VALU pipe, no LDS).
__device__ __forceinline__ float dpp8_sum(float x) {
    int t;
    t = __builtin_amdgcn_update_dpp(0, __float_as_int(x), 0xB1, 0xF, 0xF, true);  // quad_perm [1,0,3,2]
    x += __int_as_float(t);
    t = __builtin_amdgcn_update_dpp(0, __float_as_int(x), 0x4E, 0xF, 0xF, true);  // quad_perm [2,3,0,1]
    x += __int_as_float(t);
    t = __builtin_amdgcn_update_dpp(0, __float_as_int(x), 0x141, 0xF, 0xF, true); // row_half_mirror
    x += __int_as_float(t);
    return x;
}

// ---------------- zero-init (must precede ALL histogram atomics) ------------
__global__ __launch_bounds__(256) void k_zero(int* __restrict__ p, int n)
{
    int i = blockIdx.x * 256 + threadIdx.x;
    if (i < n) p[i] = 0;
}

// ---------------- Tiled GEMM + edge histogram -------------------------------
// Histogram atomics issued up front: their L2 round-trips hide under the
// GEMM's VALU work (R10 lesson: never grid.sync; R12: hide k_deg instead).
__global__ __launch_bounds__(256) void k_gemm(
    const float* __restrict__ x, const int* __restrict__ ei,
    const float* __restrict__ Wl, const float* __restrict__ bl,
    const float* __restrict__ Wr, const float* __restrict__ br,
    const float* __restrict__ Wres,
    unsigned short* __restrict__ xlh, float* __restrict__ xr,
    float* __restrict__ xres, int* __restrict__ deg)
{
    __shared__ float sX[64 * LXP];   // [node][k]
    __shared__ float sW[64 * LWP];   // [k][col]
    const int tid = threadIdx.x;
    const int n0 = blockIdx.x * 64;

    // edge histogram chunk (fire-and-forget atomics, overlap with GEMM)
    {
        const int e0 = blockIdx.x * EPB;
        const int e1 = min(e0 + EPB, NE);
        for (int e = e0 + tid; e < e1; e += 256) {
            const int d = ei[NE + e];
            if ((unsigned)d < NN) atomicAdd(&deg[d], 1);
        }
    }

    {
        const int r = tid >> 4;              // 0..15
        const int k4 = (tid & 15) * 4;
#pragma unroll
        for (int i = 0; i < 4; ++i) {
            const int node = n0 + i * 16 + r;
            float4 v = make_float4(0.f, 0.f, 0.f, 0.f);
            if (node < NN) v = *(const float4*)(x + (size_t)node * IN_CH + k4);
            *(float4*)(sX + (i * 16 + r) * LXP + k4) = v;
        }
    }

    const int tx = tid & 15;                 // col group: cols tx*8..+7
    const int ty = tid >> 4;                 // node group: nodes ty*4..+3
    const int c0 = tx * 8;

    for (int mtx = 0; mtx < 3; ++mtx) {
        const float* __restrict__ W = (mtx == 0) ? Wl : (mtx == 1) ? Wr : Wres;

        __syncthreads();
#pragma unroll
        for (int i = 0; i < 8; ++i) {
            const int idx = i * 256 + tid;   // float4 index in [64][32]
            const int k = idx >> 5;
            const int c4 = (idx & 31) * 4;
            const float4 v = *(const float4*)(W + k * HID + c4);
            *(float4*)(sW + k * LWP + c4) = v;
        }
        __syncthreads();

        float acc[4][8];
#pragma unroll
        for (int n = 0; n < 4; ++n)
#pragma unroll
            for (int c = 0; c < 8; ++c) acc[n][c] = 0.f;

        for (int k = 0; k < 64; k += 4) {
            float a[4][4];
#pragma unroll
            for (int n = 0; n < 4; ++n) {
                const float4 t = *(const float4*)(sX + (ty * 4 + n) * LXP + k);
                a[n][0] = t.x; a[n][1] = t.y; a[n][2] = t.z; a[n][3] = t.w;
            }
#pragma unroll
            for (int kk = 0; kk < 4; ++kk) {
                const float4 p0 = *(const float4*)(sW + (k + kk) * LWP + c0);
                const float4 p1 = *(const float4*)(sW + (k + kk) * LWP + c0 + 4);
                const float bv[8] = {p0.x, p0.y, p0.z, p0.w, p1.x, p1.y, p1.z, p1.w};
#pragma unroll
                for (int n = 0; n < 4; ++n) {
                    const float av = a[n][kk];
#pragma unroll
                    for (int c = 0; c < 8; ++c) acc[n][c] += av * bv[c];
                }
            }
        }

        if (mtx == 0) {
            float bias8[8];
#pragma unroll
            for (int c = 0; c < 8; ++c) bias8[c] = bl[c0 + c];
#pragma unroll
            for (int n = 0; n < 4; ++n) {
                const int node = n0 + ty * 4 + n;
                if (node < NN) {
                    uint4 pk;
                    unsigned* pp = &pk.x;
#pragma unroll
                    for (int c = 0; c < 4; ++c) {
                        const unsigned lo = bf16rn(acc[n][2 * c] + bias8[2 * c]);
                        const unsigned hi = bf16rn(acc[n][2 * c + 1] + bias8[2 * c + 1]);
                        pp[c] = lo | (hi << 16);
                    }
                    *(uint4*)(xlh + (size_t)node * HID + c0) = pk;
                }
            }
        } else {
            float* __restrict__ outp = (mtx == 1) ? xr : xres;
            float bias8[8];
#pragma unroll
            for (int c = 0; c < 8; ++c) bias8[c] = (mtx == 1) ? br[c0 + c] : 0.f;
#pragma unroll
            for (int n = 0; n < 4; ++n) {
                const int node = n0 + ty * 4 + n;
                if (node < NN) {
                    float4 o0, o1;
                    o0.x = acc[n][0] + bias8[0]; o0.y = acc[n][1] + bias8[1];
                    o0.z = acc[n][2] + bias8[2]; o0.w = acc[n][3] + bias8[3];
                    o1.x = acc[n][4] + bias8[4]; o1.y = acc[n][5] + bias8[5];
                    o1.z = acc[n][6] + bias8[6]; o1.w = acc[n][7] + bias8[7];
                    *(float4*)(outp + (size_t)node * HID + c0) = o0;
                    *(float4*)(outp + (size_t)node * HID + c0 + 4) = o1;
                }
            }
        }
    }
}

__device__ __forceinline__ int block_scan_excl(int v, int tid, int* ws)
{
    const int lane = tid & 63, w = tid >> 6;
    int incl = v;
#pragma unroll
    for (int d = 1; d < 64; d <<= 1) {
        int t = __shfl_up(incl, d, 64);
        if (lane >= d) incl += t;
    }
    if (lane == 63) ws[w] = incl;
    __syncthreads();
    int off = 0;
    for (int j = 0; j < w; ++j) off += ws[j];
    return off + incl - v;
}

__global__ __launch_bounds__(256) void k_scan1(const int* __restrict__ deg, int* __restrict__ bsum)
{
    __shared__ int ws[4];
    const int tid = threadIdx.x;
    const int i = blockIdx.x * 256 + tid;
    const int v = (i < NN) ? deg[i] : 0;
    int excl = block_scan_excl(v, tid, ws);
    if (tid == 255) bsum[blockIdx.x] = excl + v;
}

__global__ __launch_bounds__(256) void k_scan2(int* __restrict__ bsum, int* __restrict__ boff,
                                               int* __restrict__ row_ptr)
{
    __shared__ int ws[4];
    const int tid = threadIdx.x;
    const int v = (tid < SCAN_B) ? bsum[tid] : 0;
    int excl = block_scan_excl(v, tid, ws);
    if (tid < SCAN_B) boff[tid] = excl;
    if (tid == 0) row_ptr[NN] = NE;
}

__global__ __launch_bounds__(256) void k_scan3(const int* __restrict__ deg,
                                               const int* __restrict__ boff,
                                               int* __restrict__ row_ptr,
                                               int* __restrict__ cursor)
{
    __shared__ int ws[4];
    const int tid = threadIdx.x;
    const int i = blockIdx.x * 256 + tid;
    const int v = (i < NN) ? deg[i] : 0;
    int excl = block_scan_excl(v, tid, ws) + boff[blockIdx.x];
    if (i < NN) { row_ptr[i] = excl; cursor[i] = excl; }
}

__global__ __launch_bounds__(256) void k_scatter(const int* __restrict__ ei,
                                                 int* __restrict__ cursor,
                                                 int* __restrict__ col_src)
{
    int e = blockIdx.x * blockDim.x + threadIdx.x;
    if (e >= NE) return;
    const int s = ei[e];
    const int d = ei[NE + e];
    if ((unsigned)d >= NN) return;                       // defensive
    int pos = atomicAdd(&cursor[d], 1);
    if ((unsigned)pos < NE) col_src[pos] = s;            // never corrupt ws
}

// ---- Fused attention: single-pass softmax-aggregate, bf16 payload ----------
// R11 evidence: VALU-bound (74%); 16-deep batches waste ~46% of inner-loop
// slots on dead lanes (deg~Poisson(16): E[16*ceil(d/16)]=23.4 per 16 edges).
// R12: 8-deep, UNPREDICATED full batches + one predicated tail batch.
__global__ __launch_bounds__(256) void k_agg(
    const unsigned short* __restrict__ xlh, const float* __restrict__ xr,
    const float* __restrict__ xres,
    const int* __restrict__ row_ptr, const int* __restrict__ col_src,
    const float* __restrict__ att, const float* __restrict__ bias,
    float* __restrict__ hfeat)
{
    const int lane = threadIdx.x & 63;
    const int wid = __builtin_amdgcn_readfirstlane((blockIdx.x * blockDim.x + threadIdx.x) >> 6);
    const int nw = (gridDim.x * blockDim.x) >> 6;
    const int c0 = lane * 2;
    const int hh = lane >> 3;
    const int ci = (lane & 7) * 2;
    const float a0 = att[hh * OC + ci];
    const float a1 = att[hh * OC + ci + 1];
    const float b0 = bias[c0], b1 = bias[c0 + 1];

    for (int n = wid; n < NN; n += nw) {
        int beg = row_ptr[n], end = row_ptr[n + 1];      // uniform s_loads
        beg = max(beg, 0); end = min(end, NE); if (end < beg) end = beg;  // defensive
        const float2 xrn = *(const float2*)(xr + (size_t)n * HID + c0);
        const unsigned vvn = *((const unsigned*)(xlh + (size_t)n * HID) + lane);
        const float xlnx = __uint_as_float(vvn << 16);
        const float xlny = __uint_as_float(vvn & 0xffff0000u);
        const float qs = dpp8_sum(leaky(xlnx + xrn.x) * a0 + leaky(xlny + xrn.y) * a1);

        float den = __expf(qs);                 // self-loop term
        float acc0 = den * xlnx, acc1 = den * xlny;

        for (int base = beg; base < end; base += 64) {
            const int cnt = min(64, end - base);
            int sidx = 0;
            if (base + lane < end) sidx = col_src[base + lane];
            if ((unsigned)sidx >= NN) sidx = 0;          // bound all gathers
            int j = 0;
            // full batches: no per-slot predication
            for (; j + 8 <= cnt; j += 8) {
                int s[8]; unsigned vv[8];
#pragma unroll
                for (int u = 0; u < 8; ++u) s[u] = __builtin_amdgcn_readlane(sidx, j + u);
#pragma unroll
                for (int u = 0; u < 8; ++u)
                    vv[u] = *((const unsigned*)(xlh + (size_t)s[u] * HID) + lane);
#pragma unroll
                for (int u = 0; u < 8; ++u) {
                    const float vx = __uint_as_float(vv[u] << 16);
                    const float vy = __uint_as_float(vv[u] & 0xffff0000u);
                    const float q = dpp8_sum(leaky(vx + xrn.x) * a0 +
                                             leaky(vy + xrn.y) * a1);
                    const float w = __expf(q);
                    den += w;
                    acc0 += w * vx;
                    acc1 += w * vy;
                }
            }
            // tail batch (predicated); j+u <= 63 always (j<=56)
            if (j < cnt) {
                int s[8]; unsigned vv[8];
#pragma unroll
                for (int u = 0; u < 8; ++u) s[u] = __builtin_amdgcn_readlane(sidx, j + u);
#pragma unroll
                for (int u = 0; u < 8; ++u)
                    vv[u] = *((const unsigned*)(xlh + (size_t)s[u] * HID) + lane);
#pragma unroll
                for (int u = 0; u < 8; ++u) {
                    const float vx = __uint_as_float(vv[u] << 16);
                    const float vy = __uint_as_float(vv[u] & 0xffff0000u);
                    const float q = dpp8_sum(leaky(vx + xrn.x) * a0 +
                                             leaky(vy + xrn.y) * a1);
                    if (j + u < cnt) {
                        const float w = __expf(q);
                        den += w;
                        acc0 += w * vx;
                        acc1 += w * vy;
                    }
                }
            }
        }

        const float2 xrs = *(const float2*)(xres + (size_t)n * HID + c0);
        const float inv = 1.f / den;
        float2 t;
        t.x = acc0 * inv + xrs.x + b0;
        t.y = acc1 * inv + xrs.y + b1;
        *(float2*)(hfeat + (size_t)n * HID + c0) = t;
    }
}

// ---- Fused tail: per-graph {Wlin+ELU pool} + MLP ---------------------------
__global__ __launch_bounds__(256) void k_tail(
    const float* __restrict__ hfeat, const int* __restrict__ batch,
    const float* __restrict__ Wlin, const float* __restrict__ blin,
    const float* __restrict__ W1, const float* __restrict__ b1,
    const float* __restrict__ W2, const float* __restrict__ b2,
    const float* __restrict__ W3, const float* __restrict__ b3,
    float* __restrict__ out)
{
    __shared__ float sWlin[HID * 16];
    __shared__ float sblin[16];
    __shared__ float sW1[256], sb1[16], sW2[512], sb2[32], sW3[160], sb3[5];
    __shared__ float red[256][17];
    __shared__ float sg[16], sv1[16], sv2[32];
    const int g = blockIdx.x;
    const int tid = threadIdx.x;

    for (int i = tid; i < HID * 16; i += 256) sWlin[i] = Wlin[i];
    if (tid < 16)  sblin[tid] = blin[tid];
    if (tid < 256) sW1[tid] = W1[tid];
    for (int i = tid; i < 512; i += 256) sW2[i] = W2[i];
    if (tid < 160) sW3[tid] = W3[tid];
    if (tid < 16)  sb1[tid] = b1[tid];
    if (tid < 32)  sb2[tid] = b2[tid];
    if (tid < 5)   sb3[tid] = b3[tid];
    __syncthreads();

    int lo = 0, hi = NN;
    while (lo < hi) { int mid = (lo + hi) >> 1; if (batch[mid] < g) lo = mid + 1; else hi = mid; }
    int lo2 = lo, hi2 = NN;
    while (lo2 < hi2) { int mid = (lo2 + hi2) >> 1; if (batch[mid] < g + 1) lo2 = mid + 1; else hi2 = mid; }
    const int nbeg = lo, nend = lo2;

    float sum16[16];
#pragma unroll
    for (int j = 0; j < 16; ++j) sum16[j] = 0.f;

    for (int n = nbeg + tid; n < nend; n += 256) {
        float acc[16];
#pragma unroll
        for (int j = 0; j < 16; ++j) acc[j] = sblin[j];
        const float4* hrow = (const float4*)(hfeat + (size_t)n * HID);
#pragma unroll 8
        for (int kc = 0; kc < 32; ++kc) {
            const float4 v = hrow[kc];
#pragma unroll
            for (int j = 0; j < 16; ++j) {
                acc[j] += v.x * sWlin[(kc * 4 + 0) * 16 + j] + v.y * sWlin[(kc * 4 + 1) * 16 + j]
                        + v.z * sWlin[(kc * 4 + 2) * 16 + j] + v.w * sWlin[(kc * 4 + 3) * 16 + j];
            }
        }
#pragma unroll
        for (int j = 0; j < 16; ++j) {
            float o = acc[j];
            o = o > 0.f ? o : __expf(o) - 1.f;
            sum16[j] += o;
        }
    }

#pragma unroll
    for (int j = 0; j < 16; ++j) red[tid][j] = sum16[j];
    __syncthreads();
    for (int s = 128; s > 0; s >>= 1) {
        if (tid < s) {
#pragma unroll
            for (int j = 0; j < 16; ++j) red[tid][j] += red[tid + s][j];
        }
        __syncthreads();
    }

    if (tid < 16) sg[tid] = red[0][tid] / fmaxf((float)(nend - nbeg), 1.f);
    __syncthreads();
    if (tid < 16) {
        float s = sb1[tid];
#pragma unroll
        for (int c = 0; c < 16; ++c) s += sg[c] * sW1[c * 16 + tid];
        sv1[tid] = fmaxf(s, 0.f);
    }
    __syncthreads();
    if (tid < 32) {
        float s = sb2[tid];
#pragma unroll
        for (int c = 0; c < 16; ++c) s += sv1[c] * sW2[c * 32 + tid];
        sv2[tid] = fmaxf(s, 0.f);
    }
    __syncthreads();
    if (tid < 5) {
        float s = sb3[tid];
#pragma unroll
        for (int c = 0; c < 32; ++c) s += sv2[c] * sW3[c * 5 + tid];
        out[g * 5 + tid] = s;
    }
}

extern "C" void kernel_launch(void* const* d_in, const int* in_sizes, int n_in,
                              void* d_out, int out_size, void* d_ws, size_t ws_size,
                              hipStream_t stream)
{
    const float* x    = (const float*)d_in[0];
    const int*   ei   = (const int*)d_in[1];
    const int*   batch= (const int*)d_in[2];
    const float* Wl   = (const float*)d_in[3];
    const float* bl   = (const float*)d_in[4];
    const float* Wr   = (const float*)d_in[5];
    const float* br   = (const float*)d_in[6];
    const float* att  = (const float*)d_in[7];
    const float* Wres = (const float*)d_in[8];
    const float* bias = (const float*)d_in[9];
    const float* Wlin = (const float*)d_in[10];
    const float* blin = (const float*)d_in[11];
    const float* W1   = (const float*)d_in[12];
    const float* b1   = (const float*)d_in[13];
    const float* W2   = (const float*)d_in[14];
    const float* b2   = (const float*)d_in[15];
    const float* W3   = (const float*)d_in[16];
    const float* b3   = (const float*)d_in[17];
    float* out = (float*)d_out;

    uintptr_t p = (uintptr_t)d_ws;
    unsigned short* xlh = (unsigned short*)p; p += (size_t)NN * HID * 2;
    p = (p + 15) & ~(uintptr_t)15;
    float* xr     = (float*)p; p += (size_t)NN * HID * 4;
    float* xres   = (float*)p; p += (size_t)NN * HID * 4;
    float* hfeat  = (float*)p; p += (size_t)NN * HID * 4;
    int* deg      = (int*)p;   p += (size_t)NN * 4;
    int* row_ptr  = (int*)p;   p += (size_t)(NN + 1) * 4;
    int* cursor   = (int*)p;   p += (size_t)NN * 4;
    int* col_src  = (int*)p;   p += (size_t)NE * 4;
    int* bsum     = (int*)p;   p += (size_t)SCAN_B * 4;
    int* boff     = (int*)p;   p += (size_t)SCAN_B * 4;

    k_zero<<<SCAN_B, 256, 0, stream>>>(deg, NN);
    k_gemm<<<GEMM_B, 256, 0, stream>>>(x, ei, Wl, bl, Wr, br, Wres, xlh, xr, xres, deg);
    k_scan1<<<SCAN_B, 256, 0, stream>>>(deg, bsum);
    k_scan2<<<1, 256, 0, stream>>>(bsum, boff, row_ptr);
    k_scan3<<<SCAN_B, 256, 0, stream>>>(deg, boff, row_ptr, cursor);
    k_scatter<<<(NE + 255) / 256, 256, 0, stream>>>(ei, cursor, col_src);
    k_agg<<<2048, 256, 0, stream>>>(xlh, xr, xres, row_ptr, col_src, att, bias, hfeat);
    k_tail<<<NG, 256, 0, stream>>>(hfeat, batch, Wlin, blin,
                                   W1, b1, W2, b2, W3, b3, out);
}

// Round 13
// 262.629 us; speedup vs baseline: 3.1490x; 1.1613x over previous
//
#include <hip/hip_runtime.h>
#include <math.h>

#define NN 50000
#define NE 800000
#define IN_CH 64
#define HEADS 8
#define OC 16
#define HID 128
#define NG 500
#define SCAN_B ((NN + 255) / 256)   // 196
#define GB ((NN + 127) / 128)       // 391 GEMM blocks (128-node tiles)
#define HB 256                      // trailing histogram blocks
#define LWP 128                     // sW pitch (floats)

__device__ __forceinline__ float leaky(float x) { return x > 0.f ? x : 0.2f * x; }

// round-to-nearest-even f32 -> bf16 (as ushort in low bits)
__device__ __forceinline__ unsigned bf16rn(float f) {
    unsigned u = __float_as_uint(f);
    return (u + 0x7fffu + ((u >> 16) & 1u)) >> 16;
}

// Sum across the 8-lane head group using DPP (VALU pipe, no LDS).
__device__ __forceinline__ float dpp8_sum(float x) {
    int t;
    t = __builtin_amdgcn_update_dpp(0, __float_as_int(x), 0xB1, 0xF, 0xF, true);  // quad_perm [1,0,3,2]
    x += __int_as_float(t);
    t = __builtin_amdgcn_update_dpp(0, __float_as_int(x), 0x4E, 0xF, 0xF, true);  // quad_perm [2,3,0,1]
    x += __int_as_float(t);
    t = __builtin_amdgcn_update_dpp(0, __float_as_int(x), 0x141, 0xF, 0xF, true); // row_half_mirror
    x += __int_as_float(t);
    return x;
}

// ---------------- zero-init (must precede ALL histogram atomics) ------------
__global__ __launch_bounds__(256) void k_zero(int* __restrict__ p, int n)
{
    int i = blockIdx.x * 256 + threadIdx.x;
    if (i < n) p[i] = 0;
}

// ---------------- Tiled GEMM (128x128, 8x8/thread) + trailing histogram ----
// Blocks >= GB do ONLY the edge histogram (no barriers -> overlaps GEMM tail;
// R12 lesson: histogram inside GEMM blocks stalls at the first barrier's
// vmcnt drain). sX: pitch 64 with XOR-row swizzle (conflict-free a-loads).
__global__ __launch_bounds__(256) void k_gemm(
    const float* __restrict__ x, const int* __restrict__ ei,
    const float* __restrict__ Wl, const float* __restrict__ bl,
    const float* __restrict__ Wr, const float* __restrict__ br,
    const float* __restrict__ Wres,
    unsigned short* __restrict__ xlh, float* __restrict__ xr,
    float* __restrict__ xres, int* __restrict__ deg)
{
    const int tid = threadIdx.x;

    if (blockIdx.x >= GB) {            // histogram-only block
        const int hb = blockIdx.x - GB;
        const int per = (NE + HB - 1) / HB;        // 3125
        const int e0 = hb * per;
        const int e1 = min(e0 + per, NE);
        for (int e = e0 + tid; e < e1; e += 256) {
            const int d = ei[NE + e];
            if ((unsigned)d < NN) atomicAdd(&deg[d], 1);
        }
        return;
    }

    __shared__ float sX[128 * 64];   // XOR-swizzled: (r, j4) at r*64 + 4*(j4^(r&15))
    __shared__ float sW[64 * LWP];   // [k][col]
    const int n0 = blockIdx.x * 128;

    // stage X: 128 rows x 16 float4, swizzled store
#pragma unroll
    for (int i = 0; i < 8; ++i) {
        const int idx = i * 256 + tid;           // 0..2047
        const int r = idx >> 4;
        const int j = idx & 15;
        float4 v = make_float4(0.f, 0.f, 0.f, 0.f);
        if (n0 + r < NN) v = *(const float4*)(x + (size_t)(n0 + r) * IN_CH + j * 4);
        *(float4*)(sX + r * 64 + 4 * (j ^ (r & 15))) = v;
    }

    const int tx = tid & 15;                 // col group: cols tx*8..+7
    const int ty = tid >> 4;                 // 0..15; nodes ty + 16*n
    const int c0 = tx * 8;

    for (int mtx = 0; mtx < 3; ++mtx) {
        const float* __restrict__ W = (mtx == 0) ? Wl : (mtx == 1) ? Wr : Wres;

        __syncthreads();   // X staged (mtx=0) / previous compute done (mtx>0)
#pragma unroll
        for (int i = 0; i < 8; ++i) {
            const int idx = i * 256 + tid;   // float4 index in [64][32]
            const int k = idx >> 5;
            const int j = idx & 31;
            const float4 v = *(const float4*)(W + k * HID + j * 4);
            *(float4*)(sW + k * LWP + j * 4) = v;
        }
        __syncthreads();

        float acc[8][8];
#pragma unroll
        for (int n = 0; n < 8; ++n)
#pragma unroll
            for (int c = 0; c < 8; ++c) acc[n][c] = 0.f;

        for (int k = 0; k < 64; k += 4) {
            const int jx = (k >> 2);
            float a[8][4];
#pragma unroll
            for (int n = 0; n < 8; ++n) {
                const int r = ty + 16 * n;
                const float4 t = *(const float4*)(sX + r * 64 + 4 * (jx ^ ty));
                a[n][0] = t.x; a[n][1] = t.y; a[n][2] = t.z; a[n][3] = t.w;
            }
#pragma unroll
            for (int kk = 0; kk < 4; ++kk) {
                const float4 p0 = *(const float4*)(sW + (k + kk) * LWP + c0);
                const float4 p1 = *(const float4*)(sW + (k + kk) * LWP + c0 + 4);
                const float bv[8] = {p0.x, p0.y, p0.z, p0.w, p1.x, p1.y, p1.z, p1.w};
#pragma unroll
                for (int n = 0; n < 8; ++n) {
                    const float av = a[n][kk];
#pragma unroll
                    for (int c = 0; c < 8; ++c) acc[n][c] += av * bv[c];
                }
            }
        }

        if (mtx == 0) {
            float bias8[8];
#pragma unroll
            for (int c = 0; c < 8; ++c) bias8[c] = bl[c0 + c];
#pragma unroll
            for (int n = 0; n < 8; ++n) {
                const int node = n0 + ty + 16 * n;
                if (node < NN) {
                    uint4 pk;
                    unsigned* pp = &pk.x;
#pragma unroll
                    for (int c = 0; c < 4; ++c) {
                        const unsigned lo = bf16rn(acc[n][2 * c] + bias8[2 * c]);
                        const unsigned hi = bf16rn(acc[n][2 * c + 1] + bias8[2 * c + 1]);
                        pp[c] = lo | (hi << 16);
                    }
                    *(uint4*)(xlh + (size_t)node * HID + c0) = pk;
                }
            }
        } else {
            float* __restrict__ outp = (mtx == 1) ? xr : xres;
            float bias8[8];
#pragma unroll
            for (int c = 0; c < 8; ++c) bias8[c] = (mtx == 1) ? br[c0 + c] : 0.f;
#pragma unroll
            for (int n = 0; n < 8; ++n) {
                const int node = n0 + ty + 16 * n;
                if (node < NN) {
                    float4 o0, o1;
                    o0.x = acc[n][0] + bias8[0]; o0.y = acc[n][1] + bias8[1];
                    o0.z = acc[n][2] + bias8[2]; o0.w = acc[n][3] + bias8[3];
                    o1.x = acc[n][4] + bias8[4]; o1.y = acc[n][5] + bias8[5];
                    o1.z = acc[n][6] + bias8[6]; o1.w = acc[n][7] + bias8[7];
                    *(float4*)(outp + (size_t)node * HID + c0) = o0;
                    *(float4*)(outp + (size_t)node * HID + c0 + 4) = o1;
                }
            }
        }
    }
}

__device__ __forceinline__ int block_scan_excl(int v, int tid, int* ws)
{
    const int lane = tid & 63, w = tid >> 6;
    int incl = v;
#pragma unroll
    for (int d = 1; d < 64; d <<= 1) {
        int t = __shfl_up(incl, d, 64);
        if (lane >= d) incl += t;
    }
    if (lane == 63) ws[w] = incl;
    __syncthreads();
    int off = 0;
    for (int j = 0; j < w; ++j) off += ws[j];
    return off + incl - v;
}

__global__ __launch_bounds__(256) void k_scan1(const int* __restrict__ deg, int* __restrict__ bsum)
{
    __shared__ int ws[4];
    const int tid = threadIdx.x;
    const int i = blockIdx.x * 256 + tid;
    const int v = (i < NN) ? deg[i] : 0;
    int excl = block_scan_excl(v, tid, ws);
    if (tid == 255) bsum[blockIdx.x] = excl + v;
}

__global__ __launch_bounds__(256) void k_scan2(int* __restrict__ bsum, int* __restrict__ boff,
                                               int* __restrict__ row_ptr)
{
    __shared__ int ws[4];
    const int tid = threadIdx.x;
    const int v = (tid < SCAN_B) ? bsum[tid] : 0;
    int excl = block_scan_excl(v, tid, ws);
    if (tid < SCAN_B) boff[tid] = excl;
    if (tid == 0) row_ptr[NN] = NE;
}

__global__ __launch_bounds__(256) void k_scan3(const int* __restrict__ deg,
                                               const int* __restrict__ boff,
                                               int* __restrict__ row_ptr,
                                               int* __restrict__ cursor)
{
    __shared__ int ws[4];
    const int tid = threadIdx.x;
    const int i = blockIdx.x * 256 + tid;
    const int v = (i < NN) ? deg[i] : 0;
    int excl = block_scan_excl(v, tid, ws) + boff[blockIdx.x];
    if (i < NN) { row_ptr[i] = excl; cursor[i] = excl; }
}

__global__ __launch_bounds__(256) void k_scatter(const int* __restrict__ ei,
                                                 int* __restrict__ cursor,
                                                 int* __restrict__ col_src)
{
    int e = blockIdx.x * blockDim.x + threadIdx.x;
    if (e >= NE) return;
    const int s = ei[e];
    const int d = ei[NE + e];
    if ((unsigned)d >= NN) return;                       // defensive
    int pos = atomicAdd(&cursor[d], 1);
    if ((unsigned)pos < NE) col_src[pos] = s;            // never corrupt ws
}

// ---- Fused attention: single-pass softmax-aggregate, bf16 payload ----------
// 8-deep UNPREDICATED full batches + one predicated tail (R12: cut dead-slot
// VALU waste from ~46% to ~25%). exp overflow impossible (|q| <~ 10 << 88).
__global__ __launch_bounds__(256) void k_agg(
    const unsigned short* __restrict__ xlh, const float* __restrict__ xr,
    const float* __restrict__ xres,
    const int* __restrict__ row_ptr, const int* __restrict__ col_src,
    const float* __restrict__ att, const float* __restrict__ bias,
    float* __restrict__ hfeat)
{
    const int lane = threadIdx.x & 63;
    const int wid = __builtin_amdgcn_readfirstlane((blockIdx.x * blockDim.x + threadIdx.x) >> 6);
    const int nw = (gridDim.x * blockDim.x) >> 6;
    const int c0 = lane * 2;
    const int hh = lane >> 3;
    const int ci = (lane & 7) * 2;
    const float a0 = att[hh * OC + ci];
    const float a1 = att[hh * OC + ci + 1];
    const float b0 = bias[c0], b1 = bias[c0 + 1];

    for (int n = wid; n < NN; n += nw) {
        int beg = row_ptr[n], end = row_ptr[n + 1];      // uniform s_loads
        beg = max(beg, 0); end = min(end, NE); if (end < beg) end = beg;  // defensive
        const float2 xrn = *(const float2*)(xr + (size_t)n * HID + c0);
        const unsigned vvn = *((const unsigned*)(xlh + (size_t)n * HID) + lane);
        const float xlnx = __uint_as_float(vvn << 16);
        const float xlny = __uint_as_float(vvn & 0xffff0000u);
        const float qs = dpp8_sum(leaky(xlnx + xrn.x) * a0 + leaky(xlny + xrn.y) * a1);

        float den = __expf(qs);                 // self-loop term
        float acc0 = den * xlnx, acc1 = den * xlny;

        for (int base = beg; base < end; base += 64) {
            const int cnt = min(64, end - base);
            int sidx = 0;
            if (base + lane < end) sidx = col_src[base + lane];
            if ((unsigned)sidx >= NN) sidx = 0;          // bound all gathers
            int j = 0;
            for (; j + 8 <= cnt; j += 8) {
                int s[8]; unsigned vv[8];
#pragma unroll
                for (int u = 0; u < 8; ++u) s[u] = __builtin_amdgcn_readlane(sidx, j + u);
#pragma unroll
                for (int u = 0; u < 8; ++u)
                    vv[u] = *((const unsigned*)(xlh + (size_t)s[u] * HID) + lane);
#pragma unroll
                for (int u = 0; u < 8; ++u) {
                    const float vx = __uint_as_float(vv[u] << 16);
                    const float vy = __uint_as_float(vv[u] & 0xffff0000u);
                    const float q = dpp8_sum(leaky(vx + xrn.x) * a0 +
                                             leaky(vy + xrn.y) * a1);
                    const float w = __expf(q);
                    den += w;
                    acc0 += w * vx;
                    acc1 += w * vy;
                }
            }
            if (j < cnt) {
                int s[8]; unsigned vv[8];
#pragma unroll
                for (int u = 0; u < 8; ++u) s[u] = __builtin_amdgcn_readlane(sidx, j + u);
#pragma unroll
                for (int u = 0; u < 8; ++u)
                    vv[u] = *((const unsigned*)(xlh + (size_t)s[u] * HID) + lane);
#pragma unroll
                for (int u = 0; u < 8; ++u) {
                    const float vx = __uint_as_float(vv[u] << 16);
                    const float vy = __uint_as_float(vv[u] & 0xffff0000u);
                    const float q = dpp8_sum(leaky(vx + xrn.x) * a0 +
                                             leaky(vy + xrn.y) * a1);
                    if (j + u < cnt) {
                        const float w = __expf(q);
                        den += w;
                        acc0 += w * vx;
                        acc1 += w * vy;
                    }
                }
            }
        }

        const float2 xrs = *(const float2*)(xres + (size_t)n * HID + c0);
        const float inv = 1.f / den;
        float2 t;
        t.x = acc0 * inv + xrs.x + b0;
        t.y = acc1 * inv + xrs.y + b1;
        *(float2*)(hfeat + (size_t)n * HID + c0) = t;
    }
}

// ---- Fused tail: per-graph {Wlin+ELU pool} + MLP ---------------------------
__global__ __launch_bounds__(256) void k_tail(
    const float* __restrict__ hfeat, const int* __restrict__ batch,
    const float* __restrict__ Wlin, const float* __restrict__ blin,
    const float* __restrict__ W1, const float* __restrict__ b1,
    const float* __restrict__ W2, const float* __restrict__ b2,
    const float* __restrict__ W3, const float* __restrict__ b3,
    float* __restrict__ out)
{
    __shared__ float sWlin[HID * 16];
    __shared__ float sblin[16];
    __shared__ float sW1[256], sb1[16], sW2[512], sb2[32], sW3[160], sb3[5];
    __shared__ float red[256][17];
    __shared__ float sg[16], sv1[16], sv2[32];
    const int g = blockIdx.x;
    const int tid = threadIdx.x;

    for (int i = tid; i < HID * 16; i += 256) sWlin[i] = Wlin[i];
    if (tid < 16)  sblin[tid] = blin[tid];
    if (tid < 256) sW1[tid] = W1[tid];
    for (int i = tid; i < 512; i += 256) sW2[i] = W2[i];
    if (tid < 160) sW3[tid] = W3[tid];
    if (tid < 16)  sb1[tid] = b1[tid];
    if (tid < 32)  sb2[tid] = b2[tid];
    if (tid < 5)   sb3[tid] = b3[tid];
    __syncthreads();

    int lo = 0, hi = NN;
    while (lo < hi) { int mid = (lo + hi) >> 1; if (batch[mid] < g) lo = mid + 1; else hi = mid; }
    int lo2 = lo, hi2 = NN;
    while (lo2 < hi2) { int mid = (lo2 + hi2) >> 1; if (batch[mid] < g + 1) lo2 = mid + 1; else hi2 = mid; }
    const int nbeg = lo, nend = lo2;

    float sum16[16];
#pragma unroll
    for (int j = 0; j < 16; ++j) sum16[j] = 0.f;

    for (int n = nbeg + tid; n < nend; n += 256) {
        float acc[16];
#pragma unroll
        for (int j = 0; j < 16; ++j) acc[j] = sblin[j];
        const float4* hrow = (const float4*)(hfeat + (size_t)n * HID);
#pragma unroll 8
        for (int kc = 0; kc < 32; ++kc) {
            const float4 v = hrow[kc];
#pragma unroll
            for (int j = 0; j < 16; ++j) {
                acc[j] += v.x * sWlin[(kc * 4 + 0) * 16 + j] + v.y * sWlin[(kc * 4 + 1) * 16 + j]
                        + v.z * sWlin[(kc * 4 + 2) * 16 + j] + v.w * sWlin[(kc * 4 + 3) * 16 + j];
            }
        }
#pragma unroll
        for (int j = 0; j < 16; ++j) {
            float o = acc[j];
            o = o > 0.f ? o : __expf(o) - 1.f;
            sum16[j] += o;
        }
    }

#pragma unroll
    for (int j = 0; j < 16; ++j) red[tid][j] = sum16[j];
    __syncthreads();
    for (int s = 128; s > 0; s >>= 1) {
        if (tid < s) {
#pragma unroll
            for (int j = 0; j < 16; ++j) red[tid][j] += red[tid + s][j];
        }
        __syncthreads();
    }

    if (tid < 16) sg[tid] = red[0][tid] / fmaxf((float)(nend - nbeg), 1.f);
    __syncthreads();
    if (tid < 16) {
        float s = sb1[tid];
#pragma unroll
        for (int c = 0; c < 16; ++c) s += sg[c] * sW1[c * 16 + tid];
        sv1[tid] = fmaxf(s, 0.f);
    }
    __syncthreads();
    if (tid < 32) {
        float s = sb2[tid];
#pragma unroll
        for (int c = 0; c < 16; ++c) s += sv1[c] * sW2[c * 32 + tid];
        sv2[tid] = fmaxf(s, 0.f);
    }
    __syncthreads();
    if (tid < 5) {
        float s = sb3[tid];
#pragma unroll
        for (int c = 0; c < 32; ++c) s += sv2[c] * sW3[c * 5 + tid];
        out[g * 5 + tid] = s;
    }
}

extern "C" void kernel_launch(void* const* d_in, const int* in_sizes, int n_in,
                              void* d_out, int out_size, void* d_ws, size_t ws_size,
                              hipStream_t stream)
{
    const float* x    = (const float*)d_in[0];
    const int*   ei   = (const int*)d_in[1];
    const int*   batch= (const int*)d_in[2];
    const float* Wl   = (const float*)d_in[3];
    const float* bl   = (const float*)d_in[4];
    const float* Wr   = (const float*)d_in[5];
    const float* br   = (const float*)d_in[6];
    const float* att  = (const float*)d_in[7];
    const float* Wres = (const float*)d_in[8];
    const float* bias = (const float*)d_in[9];
    const float* Wlin = (const float*)d_in[10];
    const float* blin = (const float*)d_in[11];
    const float* W1   = (const float*)d_in[12];
    const float* b1   = (const float*)d_in[13];
    const float* W2   = (const float*)d_in[14];
    const float* b2   = (const float*)d_in[15];
    const float* W3   = (const float*)d_in[16];
    const float* b3   = (const float*)d_in[17];
    float* out = (float*)d_out;

    uintptr_t p = (uintptr_t)d_ws;
    unsigned short* xlh = (unsigned short*)p; p += (size_t)NN * HID * 2;
    p = (p + 15) & ~(uintptr_t)15;
    float* xr     = (float*)p; p += (size_t)NN * HID * 4;
    float* xres   = (float*)p; p += (size_t)NN * HID * 4;
    float* hfeat  = (float*)p; p += (size_t)NN * HID * 4;
    int* deg      = (int*)p;   p += (size_t)NN * 4;
    int* row_ptr  = (int*)p;   p += (size_t)(NN + 1) * 4;
    int* cursor   = (int*)p;   p += (size_t)NN * 4;
    int* col_src  = (int*)p;   p += (size_t)NE * 4;
    int* bsum     = (int*)p;   p += (size_t)SCAN_B * 4;
    int* boff     = (int*)p;   p += (size_t)SCAN_B * 4;

    k_zero<<<SCAN_B, 256, 0, stream>>>(deg, NN);
    k_gemm<<<GB + HB, 256, 0, stream>>>(x, ei, Wl, bl, Wr, br, Wres, xlh, xr, xres, deg);
    k_scan1<<<SCAN_B, 256, 0, stream>>>(deg, bsum);
    k_scan2<<<1, 256, 0, stream>>>(bsum, boff, row_ptr);
    k_scan3<<<SCAN_B, 256, 0, stream>>>(deg, boff, row_ptr, cursor);
    k_scatter<<<(NE + 255) / 256, 256, 0, stream>>>(ei, cursor, col_src);
    k_agg<<<2048, 256, 0, stream>>>(xlh, xr, xres, row_ptr, col_src, att, bias, hfeat);
    k_tail<<<NG, 256, 0, stream>>>(hfeat, batch, Wlin, blin,
                                   W1, b1, W2, b2, W3, b3, out);
}